// Round 12
// baseline (276.442 us; speedup 1.0000x reference)
//
#include <hip/hip_runtime.h>
#include <hip/hip_bf16.h>

#define B_ 2
#define S_ 2048
#define E_ 2048
#define H_ 16
#define D_ 128
#define M_ (B_*S_)
#define NQKV_ (3*E_)

typedef __attribute__((ext_vector_type(8))) short bf16x8;
typedef __attribute__((ext_vector_type(4))) float f32x4;
typedef __attribute__((ext_vector_type(4))) unsigned short u16x4;
typedef __attribute__((ext_vector_type(2))) unsigned u32x2;

__device__ __forceinline__ unsigned short f2bf(float f) {
  union { float f; unsigned u; } v; v.f = f;
  unsigned r = v.u + 0x7fffu + ((v.u >> 16) & 1u);
  return (unsigned short)(r >> 16);
}
__device__ __forceinline__ float bf2f(unsigned short h) {
  union { unsigned u; float f; } v; v.u = ((unsigned)h) << 16;
  return v.f;
}

__device__ __forceinline__ void gload_lds16(const void* g, void* l) {
  __builtin_amdgcn_global_load_lds(
      (const __attribute__((address_space(1))) unsigned*)g,
      (__attribute__((address_space(3))) unsigned*)l, 16, 0, 0);
}

// ---------------------------------------------------------------- prep
__global__ __launch_bounds__(256) void prep_kernel(
    const float* __restrict__ hs,
    const float* __restrict__ Wq, const float* __restrict__ Wk, const float* __restrict__ Wv,
    const float* __restrict__ Wo,
    const float* __restrict__ bq, const float* __restrict__ bk, const float* __restrict__ bv,
    unsigned short* __restrict__ hsb, unsigned short* __restrict__ Wqkv,
    unsigned short* __restrict__ Wob, float* __restrict__ biasqkv,
    float* __restrict__ cosT, float* __restrict__ sinT)
{
  const int seg = blockIdx.y;
  const int t0 = blockIdx.x * 256 + threadIdx.x;
  const int stride = gridDim.x * 256;
  if (seg == 0) {
    const int n = (M_*E_)/4;
    for (int i = t0; i < n; i += stride) {
      f32x4 v = ((const f32x4*)hs)[i];
      u16x4 o; o[0]=f2bf(v[0]); o[1]=f2bf(v[1]); o[2]=f2bf(v[2]); o[3]=f2bf(v[3]);
      ((u16x4*)hsb)[i] = o;
    }
  } else if (seg == 1) {
    const int n = (3*E_*E_)/4;
    for (int i = t0; i < n; i += stride) {
      int e4 = i << 2;
      int r = e4 >> 11;
      int k = e4 & 2047;
      const float* src = (r < E_) ? (Wq + ((size_t)r << 11) + k)
                       : (r < 2*E_) ? (Wk + ((size_t)(r - E_) << 11) + k)
                       : (Wv + ((size_t)(r - 2*E_) << 11) + k);
      f32x4 v = *(const f32x4*)src;
      u16x4 o; o[0]=f2bf(v[0]); o[1]=f2bf(v[1]); o[2]=f2bf(v[2]); o[3]=f2bf(v[3]);
      ((u16x4*)Wqkv)[i] = o;
    }
  } else if (seg == 2) {
    const int n = (E_*E_)/4;
    for (int i = t0; i < n; i += stride) {
      f32x4 v = ((const f32x4*)Wo)[i];
      u16x4 o; o[0]=f2bf(v[0]); o[1]=f2bf(v[1]); o[2]=f2bf(v[2]); o[3]=f2bf(v[3]);
      ((u16x4*)Wob)[i] = o;
    }
  } else if (seg == 3) {
    for (int i = t0; i < NQKV_; i += stride)
      biasqkv[i] = (i < E_) ? bq[i] : (i < 2*E_) ? bk[i - E_] : bv[i - 2*E_];
  } else {
    for (int i = t0; i < S_*64; i += stride) {
      int j = i & 63, s = i >> 6;
      float inv = exp2f(-(float)j * (13.287712379549449f / 64.0f)); // 10000^(-j/64)
      float ang = (float)s * inv;
      cosT[i] = cosf(ang);
      sinT[i] = sinf(ang);
    }
  }
}

// ================================================================ 256^2 GEMM, 2-buf,
// one barrier per K-tile, compiler-scheduled read+MFMA region.
#define STAGE8(basePtr, BUF, AB, KS, KT) do { \
    unsigned short* dst_ = lds + (BUF)*32768 + (AB)*16384 + (KS)*8192; \
    const unsigned short* src_ = (basePtr) + (KT)*64 + (KS)*32; \
    _Pragma("unroll") \
    for (int j_ = 0; j_ < 2; ++j_) { \
      int cc_ = (j_ << 9) + tid; \
      int row_ = cc_ >> 2, c2_ = cc_ & 3; \
      int sc_ = c2_ ^ ((row_ >> 1) & 3); \
      gload_lds16(src_ + (size_t)row_*K + sc_*8, (char*)dst_ + cc_*16); \
    } } while(0)

#define LDA8(DST, MH, KS, BUF) do { \
    const unsigned short* Ab_ = lds + (BUF)*32768 + (KS)*8192; \
    _Pragma("unroll") \
    for (int j_ = 0; j_ < 4; ++j_) { \
      int row_ = wr*128 + ((MH)*4 + j_)*16 + l15; \
      DST[j_] = *(const bf16x8*)(Ab_ + row_*32 + ((l4 ^ ((row_>>1)&3)) << 3)); \
    } } while(0)

#define LDB8(DST, KS, BUF) do { \
    const unsigned short* Bb_ = lds + (BUF)*32768 + 16384 + (KS)*8192; \
    _Pragma("unroll") \
    for (int j_ = 0; j_ < 4; ++j_) { \
      int row_ = wc*64 + j_*16 + l15; \
      DST[j_] = *(const bf16x8*)(Bb_ + row_*32 + ((l4 ^ ((row_>>1)&3)) << 3)); \
    } } while(0)

__global__ __launch_bounds__(512, 2) void gemm8(
    const unsigned short* __restrict__ A,
    const unsigned short* __restrict__ Bm,
    const float* __restrict__ bias,
    unsigned short* __restrict__ Cv,
    int M, int N, int K, int ldc)
{
  __shared__ __align__(16) unsigned short lds[65536];   // 128 KB, 2 buffers
  const int tid = threadIdx.x;
  const int lane = tid & 63;
  const int w = tid >> 6;             // 0..7
  const int wr = w >> 2, wc = w & 3;  // 2M x 4N, wave tile 128x64
  const int l15 = lane & 15, l4 = lane >> 4;

  const int ntile = N >> 8;
  int wg = blockIdx.x;
  const int cpx = gridDim.x >> 3;
  wg = (wg & 7) * cpx + (wg >> 3);
  const int tm = wg / ntile, tn = wg % ntile;

  const unsigned short* Abase = A + ((size_t)tm*256)*K;
  const unsigned short* Bbase = Bm + ((size_t)tn*256)*K;

  f32x4 acc[8][4] = {};

  const int NT = K >> 6;   // K-tiles of 64

  // Prologue: tile0 -> buf0 (8 loads); drain; barrier.
  STAGE8(Bbase, 0, 1, 0, 0); STAGE8(Abase, 0, 0, 0, 0);
  STAGE8(Bbase, 0, 1, 1, 0); STAGE8(Abase, 0, 0, 1, 0);
  __builtin_amdgcn_sched_barrier(0);
  asm volatile("s_waitcnt vmcnt(0)" ::: "memory");
  __builtin_amdgcn_s_barrier();

  for (int t = 0; t < NT; ++t) {
    const int cb = t & 1;
    const bool more = (t + 1 < NT);
    if (more) {
      STAGE8(Bbase, cb^1, 1, 0, t+1); STAGE8(Abase, cb^1, 0, 0, t+1);
      STAGE8(Bbase, cb^1, 1, 1, t+1); STAGE8(Abase, cb^1, 0, 1, t+1);
    }
    __builtin_amdgcn_sched_barrier(0);
    // compute: compiler-scheduled 24 ds_read + 64 MFMA region
    #pragma unroll
    for (int ks = 0; ks < 2; ++ks) {
      bf16x8 a0[4], a1[4], bv[4];
      LDA8(a0, 0, ks, cb);
      LDA8(a1, 1, ks, cb);
      LDB8(bv, ks, cb);
      #pragma unroll
      for (int mm = 0; mm < 4; ++mm)
        #pragma unroll
        for (int nn = 0; nn < 4; ++nn)
          acc[mm][nn] = __builtin_amdgcn_mfma_f32_16x16x32_bf16(a0[mm], bv[nn], acc[mm][nn], 0,0,0);
      #pragma unroll
      for (int mm = 0; mm < 4; ++mm)
        #pragma unroll
        for (int nn = 0; nn < 4; ++nn)
          acc[4+mm][nn] = __builtin_amdgcn_mfma_f32_16x16x32_bf16(a1[mm], bv[nn], acc[4+mm][nn], 0,0,0);
    }
    if (more) {
      asm volatile("s_waitcnt vmcnt(0)" ::: "memory");
      __builtin_amdgcn_s_barrier();
    }
  }

  #pragma unroll
  for (int mt = 0; mt < 8; ++mt) {
    #pragma unroll
    for (int nt = 0; nt < 4; ++nt) {
      int colg = tn*256 + wc*64 + nt*16 + l15;
      float bvv = bias[colg];
      #pragma unroll
      for (int r = 0; r < 4; ++r) {
        int rowg = tm*256 + wr*128 + mt*16 + l4*4 + r;
        Cv[(size_t)rowg*ldc + colg] = f2bf(acc[mt][nt][r] + bvv);
      }
    }
  }
}

// ================================================================ 128x256 GEMM, 3-buf,
// one barrier per K-tile, counted vmcnt(6), compiler-scheduled region.
#define STGA(BUFP, TKT, KS) do { \
    unsigned short* dst_ = lds + (BUFP)*24576 + (KS)*4096; \
    const unsigned short* src_ = Abase + (TKT)*64 + (KS)*32; \
    int cc_ = tid; int row_ = cc_ >> 2, c2_ = cc_ & 3; \
    int sc_ = c2_ ^ ((row_ >> 1) & 3); \
    gload_lds16(src_ + (size_t)row_*K + sc_*8, (char*)dst_ + cc_*16); \
  } while(0)

#define STGB(BUFP, TKT, KS) do { \
    unsigned short* dst_ = lds + (BUFP)*24576 + 8192 + (KS)*8192; \
    const unsigned short* src_ = Bbase + (TKT)*64 + (KS)*32; \
    _Pragma("unroll") \
    for (int j_ = 0; j_ < 2; ++j_) { \
      int cc_ = (j_ << 9) + tid; int row_ = cc_ >> 2, c2_ = cc_ & 3; \
      int sc_ = c2_ ^ ((row_ >> 1) & 3); \
      gload_lds16(src_ + (size_t)row_*K + sc_*8, (char*)dst_ + cc_*16); \
    } } while(0)

template<int OUT_F32>
__global__ __launch_bounds__(512, 2) void gemmA(
    const unsigned short* __restrict__ A,
    const unsigned short* __restrict__ Bm,
    const float* __restrict__ bias,
    void* __restrict__ Cv,
    int M, int N, int K, int ldc)
{
  __shared__ __align__(16) unsigned short lds[73728];   // 144 KB, 3 buffers
  const int tid = threadIdx.x;
  const int lane = tid & 63;
  const int w = tid >> 6;
  const int wr = w >> 2, wc = w & 3;  // 2M x 4N, wave tile 64x64
  const int l15 = lane & 15, l4 = lane >> 4;

  const int ntile = N >> 8;
  int wg = blockIdx.x;
  const int cpx = gridDim.x >> 3;
  wg = (wg & 7) * cpx + (wg >> 3);
  const int tm = wg / ntile, tn = wg % ntile;

  const unsigned short* Abase = A + ((size_t)tm*128)*K;
  const unsigned short* Bbase = Bm + ((size_t)tn*256)*K;

  f32x4 acc[4][4] = {};

  const int NT = K >> 6;

  STGA(0,0,0); STGB(0,0,0); STGA(0,0,1); STGB(0,0,1);
  STGA(1,1,0); STGB(1,1,0); STGA(1,1,1); STGB(1,1,1);
  __builtin_amdgcn_sched_barrier(0);
  asm volatile("s_waitcnt vmcnt(6)" ::: "memory");
  __builtin_amdgcn_s_barrier();

  int bufc = 0, bufn = 2;
  for (int i = 0; i < NT; ++i) {
    const bool st = (i + 2 < NT);
    const bool more = (i + 1 < NT);
    if (st) { STGA(bufn, i+2, 0); STGB(bufn, i+2, 0); STGA(bufn, i+2, 1); STGB(bufn, i+2, 1); }
    __builtin_amdgcn_sched_barrier(0);
    #pragma unroll
    for (int ks = 0; ks < 2; ++ks) {
      bf16x8 af[4], bv[4];
      { const unsigned short* Ab_ = lds + bufc*24576 + ks*4096;
        #pragma unroll
        for (int j = 0; j < 4; ++j) {
          int row = wr*64 + j*16 + l15;
          af[j] = *(const bf16x8*)(Ab_ + row*32 + ((l4 ^ ((row>>1)&3)) << 3)); }
        const unsigned short* Bb_ = lds + bufc*24576 + 8192 + ks*8192;
        #pragma unroll
        for (int j = 0; j < 4; ++j) {
          int row = wc*64 + j*16 + l15;
          bv[j] = *(const bf16x8*)(Bb_ + row*32 + ((l4 ^ ((row>>1)&3)) << 3)); } }
      #pragma unroll
      for (int mm = 0; mm < 4; ++mm)
        #pragma unroll
        for (int nn = 0; nn < 4; ++nn)
          acc[mm][nn] = __builtin_amdgcn_mfma_f32_16x16x32_bf16(af[mm], bv[nn], acc[mm][nn], 0,0,0);
    }
    if (st)       { asm volatile("s_waitcnt vmcnt(6)" ::: "memory"); }
    else if (more){ asm volatile("s_waitcnt vmcnt(0)" ::: "memory"); }
    if (more) __builtin_amdgcn_s_barrier();
    bufc = (bufc + 1 == 3) ? 0 : bufc + 1;
    bufn = (bufn + 1 == 3) ? 0 : bufn + 1;
  }

  #pragma unroll
  for (int mt = 0; mt < 4; ++mt) {
    #pragma unroll
    for (int nt = 0; nt < 4; ++nt) {
      int colg = tn*256 + wc*64 + nt*16 + l15;
      float bvv = bias[colg];
      #pragma unroll
      for (int r = 0; r < 4; ++r) {
        int rowg = tm*128 + wr*64 + mt*16 + l4*4 + r;
        float v = acc[mt][nt][r] + bvv;
        if (OUT_F32) ((float*)Cv)[(size_t)rowg*ldc + colg] = v;
        else ((unsigned short*)Cv)[(size_t)rowg*ldc + colg] = f2bf(v);
      }
    }
  }
}

// ---------------------------------------------------------------- RoPE (in-place on qkv)
__global__ __launch_bounds__(256) void rope_kernel(
    unsigned short* __restrict__ qkv, const float* __restrict__ cosT, const float* __restrict__ sinT)
{
  int t = blockIdx.x*256 + threadIdx.x;
  int i  = t & 63;
  int h  = (t >> 6) & 15;
  int m  = t >> 10;
  int s  = m & (S_-1);
  float c = cosT[s*64 + i], sn = sinT[s*64 + i];
  const float scale = 0.08838834764831845f * 1.4426950408889634f; // log2e/sqrt(128)
  size_t base = (size_t)m*NQKV_ + h*128;
  float q1 = bf2f(qkv[base+i]), q2 = bf2f(qkv[base+64+i]);
  qkv[base+i]    = f2bf((q1*c - q2*sn)*scale);
  qkv[base+64+i] = f2bf((q2*c + q1*sn)*scale);
  size_t kb = base + E_;
  float k1 = bf2f(qkv[kb+i]), k2 = bf2f(qkv[kb+64+i]);
  qkv[kb+i]    = f2bf(k1*c - k2*sn);
  qkv[kb+64+i] = f2bf(k2*c + k1*sn);
}

// ---------------------------------------------------------------- V transpose -> [B,H,D,S]
__global__ __launch_bounds__(256) void transv_kernel(
    const unsigned short* __restrict__ qkv, unsigned short* __restrict__ Vt)
{
  __shared__ unsigned short t[32][33];
  int bid = blockIdx.x;
  int st = bid & 63;
  int dt = (bid >> 6) & 3;
  int bh = bid >> 8;
  int b = bh >> 4, h = bh & 15;
  int tx = threadIdx.x & 31, ty = threadIdx.x >> 5;
  #pragma unroll
  for (int j = 0; j < 4; ++j) {
    int r = ty + j*8;
    t[r][tx] = qkv[(size_t)(b*S_ + st*32 + r)*NQKV_ + 2*E_ + h*128 + dt*32 + tx];
  }
  __syncthreads();
  #pragma unroll
  for (int j = 0; j < 4; ++j) {
    int r = ty + j*8;
    Vt[((size_t)bh*D_ + dt*32 + r)*S_ + st*32 + tx] = t[tx][r];
  }
}

// ---------------------------------------------------------------- flash attention
// (round-11 verified: 128 q/block, 2 q-groups/wave, K/V dbuf, cvt_pk, setprio)
__global__ __launch_bounds__(256, 2) void attn_kernel(
    const unsigned short* __restrict__ qkv, const unsigned short* __restrict__ Vt,
    unsigned short* __restrict__ Ao)
{
  __shared__ unsigned short lK[2][64*128];              // 32 KB
  __shared__ unsigned short lV[2][128*64];              // 32 KB
  __shared__ __align__(16) unsigned short lP[4*32*64];  // 16 KB
  int bid = blockIdx.x;
  bid = (bid & 7)*64 + (bid >> 3);     // chunked XCD swizzle (512 = 8*64)
  const int qt = bid & 15;
  const int bh = bid >> 4;
  const int b = bh >> 4, h = bh & 15;
  const int tid = threadIdx.x, lane = tid & 63, w = tid >> 6;
  const int l15 = lane & 15, l4 = lane >> 4;

  bf16x8 qf[2][4];
  #pragma unroll
  for (int g = 0; g < 2; ++g) {
    const int qrow = qt*128 + w*32 + g*16 + l15;
    const unsigned short* qp = qkv + (size_t)(b*S_ + qrow)*NQKV_ + h*128 + l4*8;
    #pragma unroll
    for (int f = 0; f < 4; ++f) qf[g][f] = *(const bf16x8*)(qp + f*32);
  }

  f32x4 O[2][8];
  #pragma unroll
  for (int g = 0; g < 2; ++g)
    #pragma unroll
    for (int i = 0; i < 8; ++i) O[g][i] = (f32x4){0.f,0.f,0.f,0.f};
  float mx[2] = {-1e30f,-1e30f}, lsum[2] = {0.f,0.f};

  unsigned short* myP = lP + w*(32*64);
  const int ksw = (l15 & 7) << 3;
  const size_t kbase = (size_t)b*S_*NQKV_ + E_ + (size_t)h*128;
  const size_t vbase = (size_t)bh*D_*S_;

  #define ASTAGE(bi, ktile) do { \
    _Pragma("unroll") \
    for (int i_ = 0; i_ < 4; ++i_) { \
      int cc_ = i_*256 + tid; \
      int row_ = cc_ >> 4, col_ = cc_ & 15; \
      int scol_ = col_ ^ (row_ & 7); \
      gload_lds16(qkv + kbase + (size_t)((ktile)*64 + row_)*NQKV_ + scol_*8, \
                  (char*)(&lK[bi][0]) + cc_*16); \
    } \
    _Pragma("unroll") \
    for (int i_ = 0; i_ < 4; ++i_) { \
      int cc_ = i_*256 + tid; \
      int row_ = cc_ >> 3, col_ = cc_ & 7; \
      int scol_ = col_ ^ ((row_ & 7) ^ ((row_ >> 3) & 7)); \
      gload_lds16(Vt + vbase + (size_t)row_*S_ + (ktile)*64 + scol_*8, \
                  (char*)(&lV[bi][0]) + cc_*16); \
    } } while(0)

  ASTAGE(0, 0);
  asm volatile("s_waitcnt vmcnt(0)" ::: "memory");
  __syncthreads();

  for (int it = 0; it < S_/64; ++it) {
    const int cur = it & 1;
    if (it + 1 < S_/64) ASTAGE(cur ^ 1, it + 1);
    __builtin_amdgcn_sched_barrier(0);

    f32x4 sfr[2][4];
    __builtin_amdgcn_s_setprio(1);
    #pragma unroll
    for (int nf = 0; nf < 4; ++nf) {
      f32x4 s0 = (f32x4){0.f,0.f,0.f,0.f};
      f32x4 s1 = (f32x4){0.f,0.f,0.f,0.f};
      #pragma unroll
      for (int ks = 0; ks < 4; ++ks) {
        int row = nf*16 + l15;
        int ch = (ks*4 + l4) ^ (row & 7);
        bf16x8 kf = *(const bf16x8*)(&lK[cur][0] + row*128 + ch*8);
        s0 = __builtin_amdgcn_mfma_f32_16x16x32_bf16(kf, qf[0][ks], s0, 0, 0, 0);
        s1 = __builtin_amdgcn_mfma_f32_16x16x32_bf16(kf, qf[1][ks], s1, 0, 0, 0);
      }
      sfr[0][nf] = s0; sfr[1][nf] = s1;
    }
    __builtin_amdgcn_s_setprio(0);

    float vm[2];
    #pragma unroll
    for (int g = 0; g < 2; ++g) {
      float v = -1e30f;
      #pragma unroll
      for (int nf = 0; nf < 4; ++nf)
        #pragma unroll
        for (int r = 0; r < 4; ++r) v = fmaxf(v, sfr[g][nf][r]);
      v = fmaxf(v, __shfl_xor(v, 16, 64));
      v = fmaxf(v, __shfl_xor(v, 32, 64));
      vm[g] = v;
    }

    if (__any((vm[0] > mx[0] + 8.0f) || (vm[1] > mx[1] + 8.0f))) {
      #pragma unroll
      for (int g = 0; g < 2; ++g) {
        float mn = fmaxf(mx[g], vm[g]);
        float al = __builtin_amdgcn_exp2f(mx[g] - mn);
        mx[g] = mn;
        lsum[g] *= al;
        #pragma unroll
        for (int r = 0; r < 4; ++r) {
          float ar = __shfl(al, (lane & 48) + l4*4 + r, 64);
          #pragma unroll
          for (int df = 0; df < 8; ++df) O[g][df][r] *= ar;
        }
      }
    }

    #pragma unroll
    for (int g = 0; g < 2; ++g) {
      float ps = 0.f;
      #pragma unroll
      for (int nf = 0; nf < 4; ++nf) {
        #pragma unroll
        for (int r = 0; r < 4; ++r) {
          float p = __builtin_amdgcn_exp2f(sfr[g][nf][r] - mx[g]);
          sfr[g][nf][r] = p;
          ps += p;
        }
      }
      ps += __shfl_xor(ps, 16, 64);
      ps += __shfl_xor(ps, 32, 64);
      lsum[g] += ps;
    }

    #pragma unroll
    for (int g = 0; g < 2; ++g) {
      #pragma unroll
      for (int nf = 0; nf < 4; ++nf) {
        unsigned lo, hi;
        asm("v_cvt_pk_bf16_f32 %0, %1, %2" : "=v"(lo) : "v"(sfr[g][nf][0]), "v"(sfr[g][nf][1]));
        asm("v_cvt_pk_bf16_f32 %0, %1, %2" : "=v"(hi) : "v"(sfr[g][nf][2]), "v"(sfr[g][nf][3]));
        int k0 = (nf*16 + l4*4) ^ ksw;
        u32x2 val; val[0] = lo; val[1] = hi;
        *(u32x2*)(myP + (g*16 + l15)*64 + k0) = val;
      }
    }
    asm volatile("s_waitcnt lgkmcnt(0)" ::: "memory");

    __builtin_amdgcn_s_setprio(1);
    #pragma unroll
    for (int ks2 = 0; ks2 < 2; ++ks2) {
      int kk = (ks2*32 + l4*8) ^ ksw;
      bf16x8 pf0 = *(const bf16x8*)(myP + l15*64 + kk);
      bf16x8 pf1 = *(const bf16x8*)(myP + (16 + l15)*64 + kk);
      #pragma unroll
      for (int df = 0; df < 8; ++df) {
        int row = df*16 + l15;
        int ch = (ks2*4 + l4) ^ ((row & 7) ^ ((row >> 3) & 7));
        bf16x8 vf = *(const bf16x8*)(&lV[cur][0] + row*64 + ch*8);
        O[0][df] = __builtin_amdgcn_mfma_f32_16x16x32_bf16(pf0, vf, O[0][df], 0, 0, 0);
        O[1][df] = __builtin_amdgcn_mfma_f32_16x16x32_bf16(pf1, vf, O[1][df], 0, 0, 0);
      }
    }
    __builtin_amdgcn_s_setprio(0);
    asm volatile("s_waitcnt vmcnt(0)" ::: "memory");
    __syncthreads();
  }

  #pragma unroll
  for (int g = 0; g < 2; ++g) {
    float linv = 1.0f / lsum[g];
    float inv[4];
    #pragma unroll
    for (int r = 0; r < 4; ++r) inv[r] = __shfl(linv, (lane & 48) + l4*4 + r, 64);
    #pragma unroll
    for (int df = 0; df < 8; ++df) {
      int colg = h*128 + df*16 + l15;
      #pragma unroll
      for (int r = 0; r < 4; ++r) {
        int rowg = qt*128 + w*32 + g*16 + l4*4 + r;
        Ao[(size_t)(b*S_ + rowg)*E_ + colg] = f2bf(O[g][df][r] * inv[r]);
      }
    }
  }
}

// ----------------------------------------------------------------
extern "C" void kernel_launch(void* const* d_in, const int* in_sizes, int n_in,
                              void* d_out, int out_size, void* d_ws, size_t ws_size,
                              hipStream_t stream) {
  const float* hs = (const float*)d_in[0];
  const float* Wq = (const float*)d_in[1];
  const float* bq = (const float*)d_in[2];
  const float* Wk = (const float*)d_in[3];
  const float* bk = (const float*)d_in[4];
  const float* Wv = (const float*)d_in[5];
  const float* bv = (const float*)d_in[6];
  const float* Wo = (const float*)d_in[7];
  const float* bo = (const float*)d_in[8];
  float* out = (float*)d_out;

  char* p = (char*)d_ws;
  auto alloc = [&](size_t bytes) { char* r = p; p += (bytes + 255) & ~(size_t)255; return r; };
  unsigned short* hsb  = (unsigned short*)alloc((size_t)M_*E_*2);
  unsigned short* Wqkv = (unsigned short*)alloc((size_t)NQKV_*E_*2);
  unsigned short* Wob  = (unsigned short*)alloc((size_t)E_*E_*2);
  unsigned short* qkv  = (unsigned short*)alloc((size_t)M_*NQKV_*2);
  unsigned short* Vt   = (unsigned short*)alloc((size_t)B_*H_*D_*S_*2);
  unsigned short* Ao   = (unsigned short*)alloc((size_t)M_*E_*2);
  float* biasqkv = (float*)alloc((size_t)NQKV_*4);
  float* cosT = (float*)alloc((size_t)S_*64*4);
  float* sinT = (float*)alloc((size_t)S_*64*4);

  prep_kernel<<<dim3(2048, 5), 256, 0, stream>>>(hs, Wq, Wk, Wv, Wo, bq, bk, bv,
      hsb, Wqkv, Wob, biasqkv, cosT, sinT);
  // Q+K projection: 256^2 tiles, grid 16x16 = 256 = exactly 1 round.
  gemm8<<<dim3((M_/256)*(2*E_/256)), 512, 0, stream>>>(
      hsb, Wqkv, biasqkv, qkv, M_, 2*E_, E_, NQKV_);
  // V projection: 128x256 tiles, grid 32x8 = 256 = exactly 1 round.
  gemmA<0><<<dim3((M_/128)*(E_/256)), 512, 0, stream>>>(
      hsb, Wqkv + (size_t)2*E_*E_, biasqkv + 2*E_, qkv + 2*E_, M_, E_, E_, NQKV_);
  rope_kernel<<<dim3((M_*H_*64)/256), 256, 0, stream>>>(qkv, cosT, sinT);
  transv_kernel<<<dim3(B_*H_*(D_/32)*(S_/32)), 256, 0, stream>>>(qkv, Vt);
  // attention: 128 q-rows/block, grid 32x16 = 512 = 2 blocks/CU.
  attn_kernel<<<dim3(B_*H_*(S_/128)), 256, 0, stream>>>(qkv, Vt, Ao);
  // Out projection: 128x256 tiles, grid 32x8 = 256 = exactly 1 round.
  gemmA<1><<<dim3((M_/128)*(E_/256)), 512, 0, stream>>>(
      Ao, Wob, bo, out, M_, E_, E_, E_);
}

// Round 13
// 272.065 us; speedup vs baseline: 1.0161x; 1.0161x over previous
//
#include <hip/hip_runtime.h>
#include <hip/hip_bf16.h>

#define B_ 2
#define S_ 2048
#define E_ 2048
#define H_ 16
#define D_ 128
#define M_ (B_*S_)
#define NQKV_ (3*E_)

typedef __attribute__((ext_vector_type(8))) short bf16x8;
typedef __attribute__((ext_vector_type(4))) float f32x4;
typedef __attribute__((ext_vector_type(4))) unsigned short u16x4;
typedef __attribute__((ext_vector_type(2))) unsigned u32x2;

__device__ __forceinline__ unsigned short f2bf(float f) {
  union { float f; unsigned u; } v; v.f = f;
  unsigned r = v.u + 0x7fffu + ((v.u >> 16) & 1u);
  return (unsigned short)(r >> 16);
}
__device__ __forceinline__ float bf2f(unsigned short h) {
  union { unsigned u; float f; } v; v.u = ((unsigned)h) << 16;
  return v.f;
}

__device__ __forceinline__ void gload_lds16(const void* g, void* l) {
  __builtin_amdgcn_global_load_lds(
      (const __attribute__((address_space(1))) unsigned*)g,
      (__attribute__((address_space(3))) unsigned*)l, 16, 0, 0);
}

// ---------------------------------------------------------------- prep
__global__ __launch_bounds__(256) void prep_kernel(
    const float* __restrict__ hs,
    const float* __restrict__ Wq, const float* __restrict__ Wk, const float* __restrict__ Wv,
    const float* __restrict__ Wo,
    const float* __restrict__ bq, const float* __restrict__ bk, const float* __restrict__ bv,
    unsigned short* __restrict__ hsb, unsigned short* __restrict__ Wqkv,
    unsigned short* __restrict__ Wob, float* __restrict__ biasqkv,
    float* __restrict__ cosT, float* __restrict__ sinT)
{
  const int seg = blockIdx.y;
  const int t0 = blockIdx.x * 256 + threadIdx.x;
  const int stride = gridDim.x * 256;
  if (seg == 0) {
    const int n = (M_*E_)/4;
    for (int i = t0; i < n; i += stride) {
      f32x4 v = ((const f32x4*)hs)[i];
      u16x4 o; o[0]=f2bf(v[0]); o[1]=f2bf(v[1]); o[2]=f2bf(v[2]); o[3]=f2bf(v[3]);
      ((u16x4*)hsb)[i] = o;
    }
  } else if (seg == 1) {
    const int n = (3*E_*E_)/4;
    for (int i = t0; i < n; i += stride) {
      int e4 = i << 2;
      int r = e4 >> 11;
      int k = e4 & 2047;
      const float* src = (r < E_) ? (Wq + ((size_t)r << 11) + k)
                       : (r < 2*E_) ? (Wk + ((size_t)(r - E_) << 11) + k)
                       : (Wv + ((size_t)(r - 2*E_) << 11) + k);
      f32x4 v = *(const f32x4*)src;
      u16x4 o; o[0]=f2bf(v[0]); o[1]=f2bf(v[1]); o[2]=f2bf(v[2]); o[3]=f2bf(v[3]);
      ((u16x4*)Wqkv)[i] = o;
    }
  } else if (seg == 2) {
    const int n = (E_*E_)/4;
    for (int i = t0; i < n; i += stride) {
      f32x4 v = ((const f32x4*)Wo)[i];
      u16x4 o; o[0]=f2bf(v[0]); o[1]=f2bf(v[1]); o[2]=f2bf(v[2]); o[3]=f2bf(v[3]);
      ((u16x4*)Wob)[i] = o;
    }
  } else if (seg == 3) {
    for (int i = t0; i < NQKV_; i += stride)
      biasqkv[i] = (i < E_) ? bq[i] : (i < 2*E_) ? bk[i - E_] : bv[i - 2*E_];
  } else {
    for (int i = t0; i < S_*64; i += stride) {
      int j = i & 63, s = i >> 6;
      float inv = exp2f(-(float)j * (13.287712379549449f / 64.0f)); // 10000^(-j/64)
      float ang = (float)s * inv;
      cosT[i] = cosf(ang);
      sinT[i] = sinf(ang);
    }
  }
}

// ================================================================ 256^2 GEMM, 2-buf,
// one barrier per K-tile, compiler-scheduled read+MFMA region.
// Fused RoPE epilogue: partner (col^64) exchanged through the (idle) LDS;
// Q columns (colg < nq) additionally scaled by log2e/sqrt(D).
#define STAGE8(basePtr, BUF, AB, KS, KT) do { \
    unsigned short* dst_ = lds + (BUF)*32768 + (AB)*16384 + (KS)*8192; \
    const unsigned short* src_ = (basePtr) + (KT)*64 + (KS)*32; \
    _Pragma("unroll") \
    for (int j_ = 0; j_ < 2; ++j_) { \
      int cc_ = (j_ << 9) + tid; \
      int row_ = cc_ >> 2, c2_ = cc_ & 3; \
      int sc_ = c2_ ^ ((row_ >> 1) & 3); \
      gload_lds16(src_ + (size_t)row_*K + sc_*8, (char*)dst_ + cc_*16); \
    } } while(0)

#define LDA8(DST, MH, KS, BUF) do { \
    const unsigned short* Ab_ = lds + (BUF)*32768 + (KS)*8192; \
    _Pragma("unroll") \
    for (int j_ = 0; j_ < 4; ++j_) { \
      int row_ = wr*128 + ((MH)*4 + j_)*16 + l15; \
      DST[j_] = *(const bf16x8*)(Ab_ + row_*32 + ((l4 ^ ((row_>>1)&3)) << 3)); \
    } } while(0)

#define LDB8(DST, KS, BUF) do { \
    const unsigned short* Bb_ = lds + (BUF)*32768 + 16384 + (KS)*8192; \
    _Pragma("unroll") \
    for (int j_ = 0; j_ < 4; ++j_) { \
      int row_ = wc*64 + j_*16 + l15; \
      DST[j_] = *(const bf16x8*)(Bb_ + row_*32 + ((l4 ^ ((row_>>1)&3)) << 3)); \
    } } while(0)

#define EPSW(col, row) ((col) ^ ((((row) >> 2) & 3) << 3))

__global__ __launch_bounds__(512, 2) void gemm8(
    const unsigned short* __restrict__ A,
    const unsigned short* __restrict__ Bm,
    const float* __restrict__ bias,
    unsigned short* __restrict__ Cv,
    const float* __restrict__ cosT, const float* __restrict__ sinT,
    int M, int N, int K, int ldc, int nq)
{
  __shared__ __align__(16) unsigned short lds[65536];   // 128 KB, 2 buffers
  const int tid = threadIdx.x;
  const int lane = tid & 63;
  const int w = tid >> 6;             // 0..7
  const int wr = w >> 2, wc = w & 3;  // 2M x 4N, wave tile 128x64
  const int l15 = lane & 15, l4 = lane >> 4;

  const int ntile = N >> 8;
  int wg = blockIdx.x;
  const int cpx = gridDim.x >> 3;
  wg = (wg & 7) * cpx + (wg >> 3);
  const int tm = wg / ntile, tn = wg % ntile;

  const unsigned short* Abase = A + ((size_t)tm*256)*K;
  const unsigned short* Bbase = Bm + ((size_t)tn*256)*K;

  f32x4 acc[8][4] = {};

  const int NT = K >> 6;   // K-tiles of 64

  STAGE8(Bbase, 0, 1, 0, 0); STAGE8(Abase, 0, 0, 0, 0);
  STAGE8(Bbase, 0, 1, 1, 0); STAGE8(Abase, 0, 0, 1, 0);
  __builtin_amdgcn_sched_barrier(0);
  asm volatile("s_waitcnt vmcnt(0)" ::: "memory");
  __builtin_amdgcn_s_barrier();

  for (int t = 0; t < NT; ++t) {
    const int cb = t & 1;
    const bool more = (t + 1 < NT);
    if (more) {
      STAGE8(Bbase, cb^1, 1, 0, t+1); STAGE8(Abase, cb^1, 0, 0, t+1);
      STAGE8(Bbase, cb^1, 1, 1, t+1); STAGE8(Abase, cb^1, 0, 1, t+1);
    }
    __builtin_amdgcn_sched_barrier(0);
    #pragma unroll
    for (int ks = 0; ks < 2; ++ks) {
      bf16x8 a0[4], a1[4], bv[4];
      LDA8(a0, 0, ks, cb);
      LDA8(a1, 1, ks, cb);
      LDB8(bv, ks, cb);
      #pragma unroll
      for (int mm = 0; mm < 4; ++mm)
        #pragma unroll
        for (int nn = 0; nn < 4; ++nn)
          acc[mm][nn] = __builtin_amdgcn_mfma_f32_16x16x32_bf16(a0[mm], bv[nn], acc[mm][nn], 0,0,0);
      #pragma unroll
      for (int mm = 0; mm < 4; ++mm)
        #pragma unroll
        for (int nn = 0; nn < 4; ++nn)
          acc[4+mm][nn] = __builtin_amdgcn_mfma_f32_16x16x32_bf16(a1[mm], bv[nn], acc[4+mm][nn], 0,0,0);
    }
    if (more) {
      asm volatile("s_waitcnt vmcnt(0)" ::: "memory");
      __builtin_amdgcn_s_barrier();
    }
  }

  // -------- fused RoPE epilogue --------
  const bool isQ = (tn*256) < nq;
  const float QSC = 0.08838834764831845f * 1.4426950408889634f; // log2e/sqrt(128)

  __syncthreads();   // all waves done reading K-loop LDS

  // store bf16(acc+bias) tile (256x256) into LDS
  #pragma unroll
  for (int mt = 0; mt < 8; ++mt) {
    #pragma unroll
    for (int nt = 0; nt < 4; ++nt) {
      int col = wc*64 + nt*16 + l15;
      float bvv = bias[tn*256 + col];
      #pragma unroll
      for (int r = 0; r < 4; ++r) {
        int row = wr*128 + mt*16 + l4*4 + r;
        lds[row*256 + EPSW(col, row)] = f2bf(acc[mt][nt][r] + bvv);
      }
    }
  }
  __syncthreads();

  // read partner (col^64), rotate, scale, write to qkv
  #pragma unroll
  for (int mt = 0; mt < 8; ++mt) {
    #pragma unroll
    for (int nt = 0; nt < 4; ++nt) {
      int col = wc*64 + nt*16 + l15;
      int colg = tn*256 + col;
      int j = col & 63;
      bool hi = (col >> 6) & 1;
      float bvv = bias[colg];
      #pragma unroll
      for (int r = 0; r < 4; ++r) {
        int row = wr*128 + mt*16 + l4*4 + r;
        int rowg = tm*256 + row;
        int s = rowg & (S_-1);
        float x = bf2f(f2bf(acc[mt][nt][r] + bvv));
        float pp = bf2f(lds[row*256 + EPSW(col ^ 64, row)]);
        float c = cosT[s*64 + j], sn = sinT[s*64 + j];
        float o = hi ? (x*c + pp*sn) : (x*c - pp*sn);
        if (isQ) o *= QSC;
        Cv[(size_t)rowg*ldc + colg] = f2bf(o);
      }
    }
  }
}

// ================================================================ 128x256 GEMM, 3-buf,
// one barrier per K-tile, counted vmcnt(6), compiler-scheduled region.
#define STGA(BUFP, TKT, KS) do { \
    unsigned short* dst_ = lds + (BUFP)*24576 + (KS)*4096; \
    const unsigned short* src_ = Abase + (TKT)*64 + (KS)*32; \
    int cc_ = tid; int row_ = cc_ >> 2, c2_ = cc_ & 3; \
    int sc_ = c2_ ^ ((row_ >> 1) & 3); \
    gload_lds16(src_ + (size_t)row_*K + sc_*8, (char*)dst_ + cc_*16); \
  } while(0)

#define STGB(BUFP, TKT, KS) do { \
    unsigned short* dst_ = lds + (BUFP)*24576 + 8192 + (KS)*8192; \
    const unsigned short* src_ = Bbase + (TKT)*64 + (KS)*32; \
    _Pragma("unroll") \
    for (int j_ = 0; j_ < 2; ++j_) { \
      int cc_ = (j_ << 9) + tid; int row_ = cc_ >> 2, c2_ = cc_ & 3; \
      int sc_ = c2_ ^ ((row_ >> 1) & 3); \
      gload_lds16(src_ + (size_t)row_*K + sc_*8, (char*)dst_ + cc_*16); \
    } } while(0)

template<int OUT_F32>
__global__ __launch_bounds__(512, 2) void gemmA(
    const unsigned short* __restrict__ A,
    const unsigned short* __restrict__ Bm,
    const float* __restrict__ bias,
    void* __restrict__ Cv,
    int M, int N, int K, int ldc)
{
  __shared__ __align__(16) unsigned short lds[73728];   // 144 KB, 3 buffers
  const int tid = threadIdx.x;
  const int lane = tid & 63;
  const int w = tid >> 6;
  const int wr = w >> 2, wc = w & 3;  // 2M x 4N, wave tile 64x64
  const int l15 = lane & 15, l4 = lane >> 4;

  const int ntile = N >> 8;
  int wg = blockIdx.x;
  const int cpx = gridDim.x >> 3;
  wg = (wg & 7) * cpx + (wg >> 3);
  const int tm = wg / ntile, tn = wg % ntile;

  const unsigned short* Abase = A + ((size_t)tm*128)*K;
  const unsigned short* Bbase = Bm + ((size_t)tn*256)*K;

  f32x4 acc[4][4] = {};

  const int NT = K >> 6;

  STGA(0,0,0); STGB(0,0,0); STGA(0,0,1); STGB(0,0,1);
  STGA(1,1,0); STGB(1,1,0); STGA(1,1,1); STGB(1,1,1);
  __builtin_amdgcn_sched_barrier(0);
  asm volatile("s_waitcnt vmcnt(6)" ::: "memory");
  __builtin_amdgcn_s_barrier();

  int bufc = 0, bufn = 2;
  for (int i = 0; i < NT; ++i) {
    const bool st = (i + 2 < NT);
    const bool more = (i + 1 < NT);
    if (st) { STGA(bufn, i+2, 0); STGB(bufn, i+2, 0); STGA(bufn, i+2, 1); STGB(bufn, i+2, 1); }
    __builtin_amdgcn_sched_barrier(0);
    #pragma unroll
    for (int ks = 0; ks < 2; ++ks) {
      bf16x8 af[4], bv[4];
      { const unsigned short* Ab_ = lds + bufc*24576 + ks*4096;
        #pragma unroll
        for (int j = 0; j < 4; ++j) {
          int row = wr*64 + j*16 + l15;
          af[j] = *(const bf16x8*)(Ab_ + row*32 + ((l4 ^ ((row>>1)&3)) << 3)); }
        const unsigned short* Bb_ = lds + bufc*24576 + 8192 + ks*8192;
        #pragma unroll
        for (int j = 0; j < 4; ++j) {
          int row = wc*64 + j*16 + l15;
          bv[j] = *(const bf16x8*)(Bb_ + row*32 + ((l4 ^ ((row>>1)&3)) << 3)); } }
      #pragma unroll
      for (int mm = 0; mm < 4; ++mm)
        #pragma unroll
        for (int nn = 0; nn < 4; ++nn)
          acc[mm][nn] = __builtin_amdgcn_mfma_f32_16x16x32_bf16(af[mm], bv[nn], acc[mm][nn], 0,0,0);
    }
    if (st)       { asm volatile("s_waitcnt vmcnt(6)" ::: "memory"); }
    else if (more){ asm volatile("s_waitcnt vmcnt(0)" ::: "memory"); }
    if (more) __builtin_amdgcn_s_barrier();
    bufc = (bufc + 1 == 3) ? 0 : bufc + 1;
    bufn = (bufn + 1 == 3) ? 0 : bufn + 1;
  }

  #pragma unroll
  for (int mt = 0; mt < 4; ++mt) {
    #pragma unroll
    for (int nt = 0; nt < 4; ++nt) {
      int colg = tn*256 + wc*64 + nt*16 + l15;
      float bvv = bias[colg];
      #pragma unroll
      for (int r = 0; r < 4; ++r) {
        int rowg = tm*128 + wr*64 + mt*16 + l4*4 + r;
        float v = acc[mt][nt][r] + bvv;
        if (OUT_F32) ((float*)Cv)[(size_t)rowg*ldc + colg] = v;
        else ((unsigned short*)Cv)[(size_t)rowg*ldc + colg] = f2bf(v);
      }
    }
  }
}

// ---------------------------------------------------------------- V transpose -> [B,H,D,S]
__global__ __launch_bounds__(256) void transv_kernel(
    const unsigned short* __restrict__ qkv, unsigned short* __restrict__ Vt)
{
  __shared__ unsigned short t[32][33];
  int bid = blockIdx.x;
  int st = bid & 63;
  int dt = (bid >> 6) & 3;
  int bh = bid >> 8;
  int b = bh >> 4, h = bh & 15;
  int tx = threadIdx.x & 31, ty = threadIdx.x >> 5;
  #pragma unroll
  for (int j = 0; j < 4; ++j) {
    int r = ty + j*8;
    t[r][tx] = qkv[(size_t)(b*S_ + st*32 + r)*NQKV_ + 2*E_ + h*128 + dt*32 + tx];
  }
  __syncthreads();
  #pragma unroll
  for (int j = 0; j < 4; ++j) {
    int r = ty + j*8;
    Vt[((size_t)bh*D_ + dt*32 + r)*S_ + st*32 + tx] = t[tx][r];
  }
}

// ---------------------------------------------------------------- flash attention
// (round-11 verified: 128 q/block, 2 q-groups/wave, K/V dbuf, cvt_pk, setprio)
__global__ __launch_bounds__(256, 2) void attn_kernel(
    const unsigned short* __restrict__ qkv, const unsigned short* __restrict__ Vt,
    unsigned short* __restrict__ Ao)
{
  __shared__ unsigned short lK[2][64*128];              // 32 KB
  __shared__ unsigned short lV[2][128*64];              // 32 KB
  __shared__ __align__(16) unsigned short lP[4*32*64];  // 16 KB
  int bid = blockIdx.x;
  bid = (bid & 7)*64 + (bid >> 3);     // chunked XCD swizzle (512 = 8*64)
  const int qt = bid & 15;
  const int bh = bid >> 4;
  const int b = bh >> 4, h = bh & 15;
  const int tid = threadIdx.x, lane = tid & 63, w = tid >> 6;
  const int l15 = lane & 15, l4 = lane >> 4;

  bf16x8 qf[2][4];
  #pragma unroll
  for (int g = 0; g < 2; ++g) {
    const int qrow = qt*128 + w*32 + g*16 + l15;
    const unsigned short* qp = qkv + (size_t)(b*S_ + qrow)*NQKV_ + h*128 + l4*8;
    #pragma unroll
    for (int f = 0; f < 4; ++f) qf[g][f] = *(const bf16x8*)(qp + f*32);
  }

  f32x4 O[2][8];
  #pragma unroll
  for (int g = 0; g < 2; ++g)
    #pragma unroll
    for (int i = 0; i < 8; ++i) O[g][i] = (f32x4){0.f,0.f,0.f,0.f};
  float mx[2] = {-1e30f,-1e30f}, lsum[2] = {0.f,0.f};

  unsigned short* myP = lP + w*(32*64);
  const int ksw = (l15 & 7) << 3;
  const size_t kbase = (size_t)b*S_*NQKV_ + E_ + (size_t)h*128;
  const size_t vbase = (size_t)bh*D_*S_;

  #define ASTAGE(bi, ktile) do { \
    _Pragma("unroll") \
    for (int i_ = 0; i_ < 4; ++i_) { \
      int cc_ = i_*256 + tid; \
      int row_ = cc_ >> 4, col_ = cc_ & 15; \
      int scol_ = col_ ^ (row_ & 7); \
      gload_lds16(qkv + kbase + (size_t)((ktile)*64 + row_)*NQKV_ + scol_*8, \
                  (char*)(&lK[bi][0]) + cc_*16); \
    } \
    _Pragma("unroll") \
    for (int i_ = 0; i_ < 4; ++i_) { \
      int cc_ = i_*256 + tid; \
      int row_ = cc_ >> 3, col_ = cc_ & 7; \
      int scol_ = col_ ^ ((row_ & 7) ^ ((row_ >> 3) & 7)); \
      gload_lds16(Vt + vbase + (size_t)row_*S_ + (ktile)*64 + scol_*8, \
                  (char*)(&lV[bi][0]) + cc_*16); \
    } } while(0)

  ASTAGE(0, 0);
  asm volatile("s_waitcnt vmcnt(0)" ::: "memory");
  __syncthreads();

  for (int it = 0; it < S_/64; ++it) {
    const int cur = it & 1;
    if (it + 1 < S_/64) ASTAGE(cur ^ 1, it + 1);
    __builtin_amdgcn_sched_barrier(0);

    f32x4 sfr[2][4];
    __builtin_amdgcn_s_setprio(1);
    #pragma unroll
    for (int nf = 0; nf < 4; ++nf) {
      f32x4 s0 = (f32x4){0.f,0.f,0.f,0.f};
      f32x4 s1 = (f32x4){0.f,0.f,0.f,0.f};
      #pragma unroll
      for (int ks = 0; ks < 4; ++ks) {
        int row = nf*16 + l15;
        int ch = (ks*4 + l4) ^ (row & 7);
        bf16x8 kf = *(const bf16x8*)(&lK[cur][0] + row*128 + ch*8);
        s0 = __builtin_amdgcn_mfma_f32_16x16x32_bf16(kf, qf[0][ks], s0, 0, 0, 0);
        s1 = __builtin_amdgcn_mfma_f32_16x16x32_bf16(kf, qf[1][ks], s1, 0, 0, 0);
      }
      sfr[0][nf] = s0; sfr[1][nf] = s1;
    }
    __builtin_amdgcn_s_setprio(0);

    float vm[2];
    #pragma unroll
    for (int g = 0; g < 2; ++g) {
      float v = -1e30f;
      #pragma unroll
      for (int nf = 0; nf < 4; ++nf)
        #pragma unroll
        for (int r = 0; r < 4; ++r) v = fmaxf(v, sfr[g][nf][r]);
      v = fmaxf(v, __shfl_xor(v, 16, 64));
      v = fmaxf(v, __shfl_xor(v, 32, 64));
      vm[g] = v;
    }

    if (__any((vm[0] > mx[0] + 8.0f) || (vm[1] > mx[1] + 8.0f))) {
      #pragma unroll
      for (int g = 0; g < 2; ++g) {
        float mn = fmaxf(mx[g], vm[g]);
        float al = __builtin_amdgcn_exp2f(mx[g] - mn);
        mx[g] = mn;
        lsum[g] *= al;
        #pragma unroll
        for (int r = 0; r < 4; ++r) {
          float ar = __shfl(al, (lane & 48) + l4*4 + r, 64);
          #pragma unroll
          for (int df = 0; df < 8; ++df) O[g][df][r] *= ar;
        }
      }
    }

    #pragma unroll
    for (int g = 0; g < 2; ++g) {
      float ps = 0.f;
      #pragma unroll
      for (int nf = 0; nf < 4; ++nf) {
        #pragma unroll
        for (int r = 0; r < 4; ++r) {
          float p = __builtin_amdgcn_exp2f(sfr[g][nf][r] - mx[g]);
          sfr[g][nf][r] = p;
          ps += p;
        }
      }
      ps += __shfl_xor(ps, 16, 64);
      ps += __shfl_xor(ps, 32, 64);
      lsum[g] += ps;
    }

    #pragma unroll
    for (int g = 0; g < 2; ++g) {
      #pragma unroll
      for (int nf = 0; nf < 4; ++nf) {
        unsigned lo, hi;
        asm("v_cvt_pk_bf16_f32 %0, %1, %2" : "=v"(lo) : "v"(sfr[g][nf][0]), "v"(sfr[g][nf][1]));
        asm("v_cvt_pk_bf16_f32 %0, %1, %2" : "=v"(hi) : "v"(sfr[g][nf][2]), "v"(sfr[g][nf][3]));
        int k0 = (nf*16 + l4*4) ^ ksw;
        u32x2 val; val[0] = lo; val[1] = hi;
        *(u32x2*)(myP + (g*16 + l15)*64 + k0) = val;
      }
    }
    asm volatile("s_waitcnt lgkmcnt(0)" ::: "memory");

    __builtin_amdgcn_s_setprio(1);
    #pragma unroll
    for (int ks2 = 0; ks2 < 2; ++ks2) {
      int kk = (ks2*32 + l4*8) ^ ksw;
      bf16x8 pf0 = *(const bf16x8*)(myP + l15*64 + kk);
      bf16x8 pf1 = *(const bf16x8*)(myP + (16 + l15)*64 + kk);
      #pragma unroll
      for (int df = 0; df < 8; ++df) {
        int row = df*16 + l15;
        int ch = (ks2*4 + l4) ^ ((row & 7) ^ ((row >> 3) & 7));
        bf16x8 vf = *(const bf16x8*)(&lV[cur][0] + row*64 + ch*8);
        O[0][df] = __builtin_amdgcn_mfma_f32_16x16x32_bf16(pf0, vf, O[0][df], 0, 0, 0);
        O[1][df] = __builtin_amdgcn_mfma_f32_16x16x32_bf16(pf1, vf, O[1][df], 0, 0, 0);
      }
    }
    __builtin_amdgcn_s_setprio(0);
    asm volatile("s_waitcnt vmcnt(0)" ::: "memory");
    __syncthreads();
  }

  #pragma unroll
  for (int g = 0; g < 2; ++g) {
    float linv = 1.0f / lsum[g];
    float inv[4];
    #pragma unroll
    for (int r = 0; r < 4; ++r) inv[r] = __shfl(linv, (lane & 48) + l4*4 + r, 64);
    #pragma unroll
    for (int df = 0; df < 8; ++df) {
      int colg = h*128 + df*16 + l15;
      #pragma unroll
      for (int r = 0; r < 4; ++r) {
        int rowg = qt*128 + w*32 + g*16 + l4*4 + r;
        Ao[(size_t)(b*S_ + rowg)*E_ + colg] = f2bf(O[g][df][r] * inv[r]);
      }
    }
  }
}

// ----------------------------------------------------------------
extern "C" void kernel_launch(void* const* d_in, const int* in_sizes, int n_in,
                              void* d_out, int out_size, void* d_ws, size_t ws_size,
                              hipStream_t stream) {
  const float* hs = (const float*)d_in[0];
  const float* Wq = (const float*)d_in[1];
  const float* bq = (const float*)d_in[2];
  const float* Wk = (const float*)d_in[3];
  const float* bk = (const float*)d_in[4];
  const float* Wv = (const float*)d_in[5];
  const float* bv = (const float*)d_in[6];
  const float* Wo = (const float*)d_in[7];
  const float* bo = (const float*)d_in[8];
  float* out = (float*)d_out;

  char* p = (char*)d_ws;
  auto alloc = [&](size_t bytes) { char* r = p; p += (bytes + 255) & ~(size_t)255; return r; };
  unsigned short* hsb  = (unsigned short*)alloc((size_t)M_*E_*2);
  unsigned short* Wqkv = (unsigned short*)alloc((size_t)NQKV_*E_*2);
  unsigned short* Wob  = (unsigned short*)alloc((size_t)E_*E_*2);
  unsigned short* qkv  = (unsigned short*)alloc((size_t)M_*NQKV_*2);
  unsigned short* Vt   = (unsigned short*)alloc((size_t)B_*H_*D_*S_*2);
  unsigned short* Ao   = (unsigned short*)alloc((size_t)M_*E_*2);
  float* biasqkv = (float*)alloc((size_t)NQKV_*4);
  float* cosT = (float*)alloc((size_t)S_*64*4);
  float* sinT = (float*)alloc((size_t)S_*64*4);

  prep_kernel<<<dim3(2048, 5), 256, 0, stream>>>(hs, Wq, Wk, Wv, Wo, bq, bk, bv,
      hsb, Wqkv, Wob, biasqkv, cosT, sinT);
  // Q+K projection with fused RoPE: 256^2 tiles, grid 16x16 = 256 = 1 round.
  gemm8<<<dim3((M_/256)*(2*E_/256)), 512, 0, stream>>>(
      hsb, Wqkv, biasqkv, qkv, cosT, sinT, M_, 2*E_, E_, NQKV_, E_);
  // V projection: 128x256 tiles, grid 32x8 = 256 = exactly 1 round.
  gemmA<0><<<dim3((M_/128)*(E_/256)), 512, 0, stream>>>(
      hsb, Wqkv + (size_t)2*E_*E_, biasqkv + 2*E_, qkv + 2*E_, M_, E_, E_, NQKV_);
  transv_kernel<<<dim3(B_*H_*(D_/32)*(S_/32)), 256, 0, stream>>>(qkv, Vt);
  // attention: 128 q-rows/block, grid 32x16 = 512 = 2 blocks/CU.
  attn_kernel<<<dim3(B_*H_*(S_/128)), 256, 0, stream>>>(qkv, Vt, Ao);
  // Out projection: 128x256 tiles, grid 32x8 = 256 = exactly 1 round.
  gemmA<1><<<dim3((M_/128)*(E_/256)), 512, 0, stream>>>(
      Ao, Wob, bo, out, M_, E_, E_, E_);
}

// Round 14
// 264.931 us; speedup vs baseline: 1.0435x; 1.0269x over previous
//
#include <hip/hip_runtime.h>
#include <hip/hip_bf16.h>

#define B_ 2
#define S_ 2048
#define E_ 2048
#define H_ 16
#define D_ 128
#define M_ (B_*S_)
#define NQKV_ (3*E_)

typedef __attribute__((ext_vector_type(8))) short bf16x8;
typedef __attribute__((ext_vector_type(4))) float f32x4;
typedef __attribute__((ext_vector_type(4))) unsigned short u16x4;
typedef __attribute__((ext_vector_type(2))) unsigned u32x2;

__device__ __forceinline__ unsigned short f2bf(float f) {
  union { float f; unsigned u; } v; v.f = f;
  unsigned r = v.u + 0x7fffu + ((v.u >> 16) & 1u);
  return (unsigned short)(r >> 16);
}
__device__ __forceinline__ float bf2f(unsigned short h) {
  union { unsigned u; float f; } v; v.u = ((unsigned)h) << 16;
  return v.f;
}

__device__ __forceinline__ void gload_lds16(const void* g, void* l) {
  __builtin_amdgcn_global_load_lds(
      (const __attribute__((address_space(1))) unsigned*)g,
      (__attribute__((address_space(3))) unsigned*)l, 16, 0, 0);
}

// ---------------------------------------------------------------- prep
__global__ __launch_bounds__(256) void prep_kernel(
    const float* __restrict__ hs,
    const float* __restrict__ Wq, const float* __restrict__ Wk, const float* __restrict__ Wv,
    const float* __restrict__ Wo,
    const float* __restrict__ bq, const float* __restrict__ bk, const float* __restrict__ bv,
    unsigned short* __restrict__ hsb, unsigned short* __restrict__ Wqkv,
    unsigned short* __restrict__ Wob, float* __restrict__ biasqkv,
    float* __restrict__ cosT, float* __restrict__ sinT)
{
  const int seg = blockIdx.y;
  const int t0 = blockIdx.x * 256 + threadIdx.x;
  const int stride = gridDim.x * 256;
  if (seg == 0) {
    const int n = (M_*E_)/4;
    for (int i = t0; i < n; i += stride) {
      f32x4 v = ((const f32x4*)hs)[i];
      u16x4 o; o[0]=f2bf(v[0]); o[1]=f2bf(v[1]); o[2]=f2bf(v[2]); o[3]=f2bf(v[3]);
      ((u16x4*)hsb)[i] = o;
    }
  } else if (seg == 1) {
    const int n = (3*E_*E_)/4;
    for (int i = t0; i < n; i += stride) {
      int e4 = i << 2;
      int r = e4 >> 11;
      int k = e4 & 2047;
      const float* src = (r < E_) ? (Wq + ((size_t)r << 11) + k)
                       : (r < 2*E_) ? (Wk + ((size_t)(r - E_) << 11) + k)
                       : (Wv + ((size_t)(r - 2*E_) << 11) + k);
      f32x4 v = *(const f32x4*)src;
      u16x4 o; o[0]=f2bf(v[0]); o[1]=f2bf(v[1]); o[2]=f2bf(v[2]); o[3]=f2bf(v[3]);
      ((u16x4*)Wqkv)[i] = o;
    }
  } else if (seg == 2) {
    const int n = (E_*E_)/4;
    for (int i = t0; i < n; i += stride) {
      f32x4 v = ((const f32x4*)Wo)[i];
      u16x4 o; o[0]=f2bf(v[0]); o[1]=f2bf(v[1]); o[2]=f2bf(v[2]); o[3]=f2bf(v[3]);
      ((u16x4*)Wob)[i] = o;
    }
  } else if (seg == 3) {
    for (int i = t0; i < NQKV_; i += stride)
      biasqkv[i] = (i < E_) ? bq[i] : (i < 2*E_) ? bk[i - E_] : bv[i - 2*E_];
  } else {
    for (int i = t0; i < S_*64; i += stride) {
      int j = i & 63, s = i >> 6;
      float inv = exp2f(-(float)j * (13.287712379549449f / 64.0f)); // 10000^(-j/64)
      float ang = (float)s * inv;
      cosT[i] = cosf(ang);
      sinT[i] = sinf(ang);
    }
  }
}

// ================================================================ 256^2 GEMM, 2-buf,
// one barrier per K-tile, compiler-scheduled read+MFMA region.
// Fused RoPE epilogue (partner col^64 through LDS; Q cols scaled).
#define STAGE8(basePtr, BUF, AB, KS, KT) do { \
    unsigned short* dst_ = lds + (BUF)*32768 + (AB)*16384 + (KS)*8192; \
    const unsigned short* src_ = (basePtr) + (KT)*64 + (KS)*32; \
    _Pragma("unroll") \
    for (int j_ = 0; j_ < 2; ++j_) { \
      int cc_ = (j_ << 9) + tid; \
      int row_ = cc_ >> 2, c2_ = cc_ & 3; \
      int sc_ = c2_ ^ ((row_ >> 1) & 3); \
      gload_lds16(src_ + (size_t)row_*K + sc_*8, (char*)dst_ + cc_*16); \
    } } while(0)

#define LDA8(DST, MH, KS, BUF) do { \
    const unsigned short* Ab_ = lds + (BUF)*32768 + (KS)*8192; \
    _Pragma("unroll") \
    for (int j_ = 0; j_ < 4; ++j_) { \
      int row_ = wr*128 + ((MH)*4 + j_)*16 + l15; \
      DST[j_] = *(const bf16x8*)(Ab_ + row_*32 + ((l4 ^ ((row_>>1)&3)) << 3)); \
    } } while(0)

#define LDB8(DST, KS, BUF) do { \
    const unsigned short* Bb_ = lds + (BUF)*32768 + 16384 + (KS)*8192; \
    _Pragma("unroll") \
    for (int j_ = 0; j_ < 4; ++j_) { \
      int row_ = wc*64 + j_*16 + l15; \
      DST[j_] = *(const bf16x8*)(Bb_ + row_*32 + ((l4 ^ ((row_>>1)&3)) << 3)); \
    } } while(0)

#define EPSW(col, row) ((col) ^ ((((row) >> 2) & 3) << 3))

__global__ __launch_bounds__(512, 2) void gemm8(
    const unsigned short* __restrict__ A,
    const unsigned short* __restrict__ Bm,
    const float* __restrict__ bias,
    unsigned short* __restrict__ Cv,
    const float* __restrict__ cosT, const float* __restrict__ sinT,
    int M, int N, int K, int ldc, int nq)
{
  __shared__ __align__(16) unsigned short lds[65536];   // 128 KB, 2 buffers
  const int tid = threadIdx.x;
  const int lane = tid & 63;
  const int w = tid >> 6;             // 0..7
  const int wr = w >> 2, wc = w & 3;  // 2M x 4N, wave tile 128x64
  const int l15 = lane & 15, l4 = lane >> 4;

  const int ntile = N >> 8;
  int wg = blockIdx.x;
  const int cpx = gridDim.x >> 3;
  wg = (wg & 7) * cpx + (wg >> 3);
  const int tm = wg / ntile, tn = wg % ntile;

  const unsigned short* Abase = A + ((size_t)tm*256)*K;
  const unsigned short* Bbase = Bm + ((size_t)tn*256)*K;

  f32x4 acc[8][4] = {};

  const int NT = K >> 6;   // K-tiles of 64

  STAGE8(Bbase, 0, 1, 0, 0); STAGE8(Abase, 0, 0, 0, 0);
  STAGE8(Bbase, 0, 1, 1, 0); STAGE8(Abase, 0, 0, 1, 0);
  __builtin_amdgcn_sched_barrier(0);
  asm volatile("s_waitcnt vmcnt(0)" ::: "memory");
  __builtin_amdgcn_s_barrier();

  for (int t = 0; t < NT; ++t) {
    const int cb = t & 1;
    const bool more = (t + 1 < NT);
    if (more) {
      STAGE8(Bbase, cb^1, 1, 0, t+1); STAGE8(Abase, cb^1, 0, 0, t+1);
      STAGE8(Bbase, cb^1, 1, 1, t+1); STAGE8(Abase, cb^1, 0, 1, t+1);
    }
    __builtin_amdgcn_sched_barrier(0);
    #pragma unroll
    for (int ks = 0; ks < 2; ++ks) {
      bf16x8 a0[4], a1[4], bv[4];
      LDA8(a0, 0, ks, cb);
      LDA8(a1, 1, ks, cb);
      LDB8(bv, ks, cb);
      #pragma unroll
      for (int mm = 0; mm < 4; ++mm)
        #pragma unroll
        for (int nn = 0; nn < 4; ++nn)
          acc[mm][nn] = __builtin_amdgcn_mfma_f32_16x16x32_bf16(a0[mm], bv[nn], acc[mm][nn], 0,0,0);
      #pragma unroll
      for (int mm = 0; mm < 4; ++mm)
        #pragma unroll
        for (int nn = 0; nn < 4; ++nn)
          acc[4+mm][nn] = __builtin_amdgcn_mfma_f32_16x16x32_bf16(a1[mm], bv[nn], acc[4+mm][nn], 0,0,0);
    }
    if (more) {
      asm volatile("s_waitcnt vmcnt(0)" ::: "memory");
      __builtin_amdgcn_s_barrier();
    }
  }

  // -------- fused RoPE epilogue --------
  const bool isQ = (tn*256) < nq;
  const float QSC = 0.08838834764831845f * 1.4426950408889634f; // log2e/sqrt(128)

  __syncthreads();

  #pragma unroll
  for (int mt = 0; mt < 8; ++mt) {
    #pragma unroll
    for (int nt = 0; nt < 4; ++nt) {
      int col = wc*64 + nt*16 + l15;
      float bvv = bias[tn*256 + col];
      #pragma unroll
      for (int r = 0; r < 4; ++r) {
        int row = wr*128 + mt*16 + l4*4 + r;
        lds[row*256 + EPSW(col, row)] = f2bf(acc[mt][nt][r] + bvv);
      }
    }
  }
  __syncthreads();

  #pragma unroll
  for (int mt = 0; mt < 8; ++mt) {
    #pragma unroll
    for (int nt = 0; nt < 4; ++nt) {
      int col = wc*64 + nt*16 + l15;
      int colg = tn*256 + col;
      int j = col & 63;
      bool hi = (col >> 6) & 1;
      float bvv = bias[colg];
      #pragma unroll
      for (int r = 0; r < 4; ++r) {
        int row = wr*128 + mt*16 + l4*4 + r;
        int rowg = tm*256 + row;
        int s = rowg & (S_-1);
        float x = bf2f(f2bf(acc[mt][nt][r] + bvv));
        float pp = bf2f(lds[row*256 + EPSW(col ^ 64, row)]);
        float c = cosT[s*64 + j], sn = sinT[s*64 + j];
        float o = hi ? (x*c + pp*sn) : (x*c - pp*sn);
        if (isQ) o *= QSC;
        Cv[(size_t)rowg*ldc + colg] = f2bf(o);
      }
    }
  }
}

// ================================================================ 128x256 GEMM, 3-buf,
// one barrier per K-tile, counted vmcnt(6), compiler-scheduled region.
#define STGA(BUFP, TKT, KS) do { \
    unsigned short* dst_ = lds + (BUFP)*24576 + (KS)*4096; \
    const unsigned short* src_ = Abase + (TKT)*64 + (KS)*32; \
    int cc_ = tid; int row_ = cc_ >> 2, c2_ = cc_ & 3; \
    int sc_ = c2_ ^ ((row_ >> 1) & 3); \
    gload_lds16(src_ + (size_t)row_*K + sc_*8, (char*)dst_ + cc_*16); \
  } while(0)

#define STGB(BUFP, TKT, KS) do { \
    unsigned short* dst_ = lds + (BUFP)*24576 + 8192 + (KS)*8192; \
    const unsigned short* src_ = Bbase + (TKT)*64 + (KS)*32; \
    _Pragma("unroll") \
    for (int j_ = 0; j_ < 2; ++j_) { \
      int cc_ = (j_ << 9) + tid; int row_ = cc_ >> 2, c2_ = cc_ & 3; \
      int sc_ = c2_ ^ ((row_ >> 1) & 3); \
      gload_lds16(src_ + (size_t)row_*K + sc_*8, (char*)dst_ + cc_*16); \
    } } while(0)

// K-loop body shared by gemmA / gemmVt (identical ledger, refcheck-passed)
#define GEMMA_KLOOP() do { \
  STGA(0,0,0); STGB(0,0,0); STGA(0,0,1); STGB(0,0,1); \
  STGA(1,1,0); STGB(1,1,0); STGA(1,1,1); STGB(1,1,1); \
  __builtin_amdgcn_sched_barrier(0); \
  asm volatile("s_waitcnt vmcnt(6)" ::: "memory"); \
  __builtin_amdgcn_s_barrier(); \
  int bufc = 0, bufn = 2; \
  for (int i = 0; i < NT; ++i) { \
    const bool st = (i + 2 < NT); \
    const bool more = (i + 1 < NT); \
    if (st) { STGA(bufn, i+2, 0); STGB(bufn, i+2, 0); STGA(bufn, i+2, 1); STGB(bufn, i+2, 1); } \
    __builtin_amdgcn_sched_barrier(0); \
    _Pragma("unroll") \
    for (int ks = 0; ks < 2; ++ks) { \
      bf16x8 af[4], bvv[4]; \
      { const unsigned short* Ab_ = lds + bufc*24576 + ks*4096; \
        _Pragma("unroll") \
        for (int j = 0; j < 4; ++j) { \
          int row = wr*64 + j*16 + l15; \
          af[j] = *(const bf16x8*)(Ab_ + row*32 + ((l4 ^ ((row>>1)&3)) << 3)); } \
        const unsigned short* Bb_ = lds + bufc*24576 + 8192 + ks*8192; \
        _Pragma("unroll") \
        for (int j = 0; j < 4; ++j) { \
          int row = wc*64 + j*16 + l15; \
          bvv[j] = *(const bf16x8*)(Bb_ + row*32 + ((l4 ^ ((row>>1)&3)) << 3)); } } \
      _Pragma("unroll") \
      for (int mm = 0; mm < 4; ++mm) \
        _Pragma("unroll") \
        for (int nn = 0; nn < 4; ++nn) \
          acc[mm][nn] = __builtin_amdgcn_mfma_f32_16x16x32_bf16(af[mm], bvv[nn], acc[mm][nn], 0,0,0); \
    } \
    if (st)       { asm volatile("s_waitcnt vmcnt(6)" ::: "memory"); } \
    else if (more){ asm volatile("s_waitcnt vmcnt(0)" ::: "memory"); } \
    if (more) __builtin_amdgcn_s_barrier(); \
    bufc = (bufc + 1 == 3) ? 0 : bufc + 1; \
    bufn = (bufn + 1 == 3) ? 0 : bufn + 1; \
  } } while(0)

template<int OUT_F32>
__global__ __launch_bounds__(512, 2) void gemmA(
    const unsigned short* __restrict__ A,
    const unsigned short* __restrict__ Bm,
    const float* __restrict__ bias,
    void* __restrict__ Cv,
    int M, int N, int K, int ldc)
{
  __shared__ __align__(16) unsigned short lds[73728];   // 144 KB, 3 buffers
  const int tid = threadIdx.x;
  const int lane = tid & 63;
  const int w = tid >> 6;
  const int wr = w >> 2, wc = w & 3;  // wave tile 64x64
  const int l15 = lane & 15, l4 = lane >> 4;

  const int ntile = N >> 8;
  int wg = blockIdx.x;
  const int cpx = gridDim.x >> 3;
  wg = (wg & 7) * cpx + (wg >> 3);
  const int tm = wg / ntile, tn = wg % ntile;

  const unsigned short* Abase = A + ((size_t)tm*128)*K;
  const unsigned short* Bbase = Bm + ((size_t)tn*256)*K;

  f32x4 acc[4][4] = {};
  const int NT = K >> 6;

  GEMMA_KLOOP();

  #pragma unroll
  for (int mt = 0; mt < 4; ++mt) {
    #pragma unroll
    for (int nt = 0; nt < 4; ++nt) {
      int colg = tn*256 + wc*64 + nt*16 + l15;
      float bvv = bias[colg];
      #pragma unroll
      for (int r = 0; r < 4; ++r) {
        int rowg = tm*128 + wr*64 + mt*16 + l4*4 + r;
        float v = acc[mt][nt][r] + bvv;
        if (OUT_F32) ((float*)Cv)[(size_t)rowg*ldc + colg] = v;
        else ((unsigned short*)Cv)[(size_t)rowg*ldc + colg] = f2bf(v);
      }
    }
  }
}

// --------- V projection with fused transpose: writes Vt[bh][d][s] directly.
__global__ __launch_bounds__(512, 2) void gemmVt(
    const unsigned short* __restrict__ A,
    const unsigned short* __restrict__ Bm,
    const float* __restrict__ bias,
    unsigned short* __restrict__ Vt,
    int M, int N, int K)
{
  __shared__ __align__(16) unsigned short lds[73728];   // 144 KB
  const int tid = threadIdx.x;
  const int lane = tid & 63;
  const int w = tid >> 6;
  const int wr = w >> 2, wc = w & 3;
  const int l15 = lane & 15, l4 = lane >> 4;

  const int ntile = N >> 8;
  int wg = blockIdx.x;
  const int cpx = gridDim.x >> 3;
  wg = (wg & 7) * cpx + (wg >> 3);
  const int tm = wg / ntile, tn = wg % ntile;

  const unsigned short* Abase = A + ((size_t)tm*128)*K;
  const unsigned short* Bbase = Bm + ((size_t)tn*256)*K;

  f32x4 acc[4][4] = {};
  const int NT = K >> 6;

  GEMMA_KLOOP();

  // ---- transpose epilogue: tileT[col][row] in LDS, then coalesced Vt write
  __syncthreads();
  #pragma unroll
  for (int mt = 0; mt < 4; ++mt) {
    #pragma unroll
    for (int nt = 0; nt < 4; ++nt) {
      int col = wc*64 + nt*16 + l15;
      float bvv = bias[tn*256 + col];
      int row0 = wr*64 + mt*16 + l4*4;
      u16x4 pk;
      #pragma unroll
      for (int r = 0; r < 4; ++r) pk[r] = f2bf(acc[mt][nt][r] + bvv);
      *(u16x4*)(lds + col*128 + (row0 ^ ((col & 15) << 2))) = pk;
    }
  }
  __syncthreads();

  const int bb = (tm*128) >> 11;          // batch of this row-tile
  const int s0 = (tm*128) & (S_-1);       // seq offset
  #pragma unroll
  for (int cc = 0; cc < 8; ++cc) {
    int colL = w*32 + cc*4 + l4;
    int colg = tn*256 + colL;
    int h = colg >> 7, d = colg & 127;
    int sw = (colL & 15) << 2;
    int r0 = l15*8;
    u16x4 lo = *(const u16x4*)(lds + colL*128 + (r0 ^ sw));
    u16x4 hi = *(const u16x4*)(lds + colL*128 + ((r0 + 4) ^ sw));
    unsigned short* dst = Vt + ((size_t)((bb*16 + h)*128 + d))*S_ + s0 + r0;
    *(u16x4*)dst = lo;
    *(u16x4*)(dst + 4) = hi;
  }
}

// ---------------------------------------------------------------- flash attention
// (round-11 verified: 128 q/block, 2 q-groups/wave, K/V dbuf, cvt_pk, setprio)
__global__ __launch_bounds__(256, 2) void attn_kernel(
    const unsigned short* __restrict__ qkv, const unsigned short* __restrict__ Vt,
    unsigned short* __restrict__ Ao)
{
  __shared__ unsigned short lK[2][64*128];              // 32 KB
  __shared__ unsigned short lV[2][128*64];              // 32 KB
  __shared__ __align__(16) unsigned short lP[4*32*64];  // 16 KB
  int bid = blockIdx.x;
  bid = (bid & 7)*64 + (bid >> 3);     // chunked XCD swizzle (512 = 8*64)
  const int qt = bid & 15;
  const int bh = bid >> 4;
  const int b = bh >> 4, h = bh & 15;
  const int tid = threadIdx.x, lane = tid & 63, w = tid >> 6;
  const int l15 = lane & 15, l4 = lane >> 4;

  bf16x8 qf[2][4];
  #pragma unroll
  for (int g = 0; g < 2; ++g) {
    const int qrow = qt*128 + w*32 + g*16 + l15;
    const unsigned short* qp = qkv + (size_t)(b*S_ + qrow)*NQKV_ + h*128 + l4*8;
    #pragma unroll
    for (int f = 0; f < 4; ++f) qf[g][f] = *(const bf16x8*)(qp + f*32);
  }

  f32x4 O[2][8];
  #pragma unroll
  for (int g = 0; g < 2; ++g)
    #pragma unroll
    for (int i = 0; i < 8; ++i) O[g][i] = (f32x4){0.f,0.f,0.f,0.f};
  float mx[2] = {-1e30f,-1e30f}, lsum[2] = {0.f,0.f};

  unsigned short* myP = lP + w*(32*64);
  const int ksw = (l15 & 7) << 3;
  const size_t kbase = (size_t)b*S_*NQKV_ + E_ + (size_t)h*128;
  const size_t vbase = (size_t)bh*D_*S_;

  #define ASTAGE(bi, ktile) do { \
    _Pragma("unroll") \
    for (int i_ = 0; i_ < 4; ++i_) { \
      int cc_ = i_*256 + tid; \
      int row_ = cc_ >> 4, col_ = cc_ & 15; \
      int scol_ = col_ ^ (row_ & 7); \
      gload_lds16(qkv + kbase + (size_t)((ktile)*64 + row_)*NQKV_ + scol_*8, \
                  (char*)(&lK[bi][0]) + cc_*16); \
    } \
    _Pragma("unroll") \
    for (int i_ = 0; i_ < 4; ++i_) { \
      int cc_ = i_*256 + tid; \
      int row_ = cc_ >> 3, col_ = cc_ & 7; \
      int scol_ = col_ ^ ((row_ & 7) ^ ((row_ >> 3) & 7)); \
      gload_lds16(Vt + vbase + (size_t)row_*S_ + (ktile)*64 + scol_*8, \
                  (char*)(&lV[bi][0]) + cc_*16); \
    } } while(0)

  ASTAGE(0, 0);
  asm volatile("s_waitcnt vmcnt(0)" ::: "memory");
  __syncthreads();

  for (int it = 0; it < S_/64; ++it) {
    const int cur = it & 1;
    if (it + 1 < S_/64) ASTAGE(cur ^ 1, it + 1);
    __builtin_amdgcn_sched_barrier(0);

    f32x4 sfr[2][4];
    __builtin_amdgcn_s_setprio(1);
    #pragma unroll
    for (int nf = 0; nf < 4; ++nf) {
      f32x4 s0 = (f32x4){0.f,0.f,0.f,0.f};
      f32x4 s1 = (f32x4){0.f,0.f,0.f,0.f};
      #pragma unroll
      for (int ks = 0; ks < 4; ++ks) {
        int row = nf*16 + l15;
        int ch = (ks*4 + l4) ^ (row & 7);
        bf16x8 kf = *(const bf16x8*)(&lK[cur][0] + row*128 + ch*8);
        s0 = __builtin_amdgcn_mfma_f32_16x16x32_bf16(kf, qf[0][ks], s0, 0, 0, 0);
        s1 = __builtin_amdgcn_mfma_f32_16x16x32_bf16(kf, qf[1][ks], s1, 0, 0, 0);
      }
      sfr[0][nf] = s0; sfr[1][nf] = s1;
    }
    __builtin_amdgcn_s_setprio(0);

    float vm[2];
    #pragma unroll
    for (int g = 0; g < 2; ++g) {
      float v = -1e30f;
      #pragma unroll
      for (int nf = 0; nf < 4; ++nf)
        #pragma unroll
        for (int r = 0; r < 4; ++r) v = fmaxf(v, sfr[g][nf][r]);
      v = fmaxf(v, __shfl_xor(v, 16, 64));
      v = fmaxf(v, __shfl_xor(v, 32, 64));
      vm[g] = v;
    }

    if (__any((vm[0] > mx[0] + 8.0f) || (vm[1] > mx[1] + 8.0f))) {
      #pragma unroll
      for (int g = 0; g < 2; ++g) {
        float mn = fmaxf(mx[g], vm[g]);
        float al = __builtin_amdgcn_exp2f(mx[g] - mn);
        mx[g] = mn;
        lsum[g] *= al;
        #pragma unroll
        for (int r = 0; r < 4; ++r) {
          float ar = __shfl(al, (lane & 48) + l4*4 + r, 64);
          #pragma unroll
          for (int df = 0; df < 8; ++df) O[g][df][r] *= ar;
        }
      }
    }

    #pragma unroll
    for (int g = 0; g < 2; ++g) {
      float ps = 0.f;
      #pragma unroll
      for (int nf = 0; nf < 4; ++nf) {
        #pragma unroll
        for (int r = 0; r < 4; ++r) {
          float p = __builtin_amdgcn_exp2f(sfr[g][nf][r] - mx[g]);
          sfr[g][nf][r] = p;
          ps += p;
        }
      }
      ps += __shfl_xor(ps, 16, 64);
      ps += __shfl_xor(ps, 32, 64);
      lsum[g] += ps;
    }

    #pragma unroll
    for (int g = 0; g < 2; ++g) {
      #pragma unroll
      for (int nf = 0; nf < 4; ++nf) {
        unsigned lo, hi;
        asm("v_cvt_pk_bf16_f32 %0, %1, %2" : "=v"(lo) : "v"(sfr[g][nf][0]), "v"(sfr[g][nf][1]));
        asm("v_cvt_pk_bf16_f32 %0, %1, %2" : "=v"(hi) : "v"(sfr[g][nf][2]), "v"(sfr[g][nf][3]));
        int k0 = (nf*16 + l4*4) ^ ksw;
        u32x2 val; val[0] = lo; val[1] = hi;
        *(u32x2*)(myP + (g*16 + l15)*64 + k0) = val;
      }
    }
    asm volatile("s_waitcnt lgkmcnt(0)" ::: "memory");

    __builtin_amdgcn_s_setprio(1);
    #pragma unroll
    for (int ks2 = 0; ks2 < 2; ++ks2) {
      int kk = (ks2*32 + l4*8) ^ ksw;
      bf16x8 pf0 = *(const bf16x8*)(myP + l15*64 + kk);
      bf16x8 pf1 = *(const bf16x8*)(myP + (16 + l15)*64 + kk);
      #pragma unroll
      for (int df = 0; df < 8; ++df) {
        int row = df*16 + l15;
        int ch = (ks2*4 + l4) ^ ((row & 7) ^ ((row >> 3) & 7));
        bf16x8 vf = *(const bf16x8*)(&lV[cur][0] + row*64 + ch*8);
        O[0][df] = __builtin_amdgcn_mfma_f32_16x16x32_bf16(pf0, vf, O[0][df], 0, 0, 0);
        O[1][df] = __builtin_amdgcn_mfma_f32_16x16x32_bf16(pf1, vf, O[1][df], 0, 0, 0);
      }
    }
    __builtin_amdgcn_s_setprio(0);
    asm volatile("s_waitcnt vmcnt(0)" ::: "memory");
    __syncthreads();
  }

  #pragma unroll
  for (int g = 0; g < 2; ++g) {
    float linv = 1.0f / lsum[g];
    float inv[4];
    #pragma unroll
    for (int r = 0; r < 4; ++r) inv[r] = __shfl(linv, (lane & 48) + l4*4 + r, 64);
    #pragma unroll
    for (int df = 0; df < 8; ++df) {
      int colg = h*128 + df*16 + l15;
      #pragma unroll
      for (int r = 0; r < 4; ++r) {
        int rowg = qt*128 + w*32 + g*16 + l4*4 + r;
        Ao[(size_t)(b*S_ + rowg)*E_ + colg] = f2bf(O[g][df][r] * inv[r]);
      }
    }
  }
}

// ----------------------------------------------------------------
extern "C" void kernel_launch(void* const* d_in, const int* in_sizes, int n_in,
                              void* d_out, int out_size, void* d_ws, size_t ws_size,
                              hipStream_t stream) {
  const float* hs = (const float*)d_in[0];
  const float* Wq = (const float*)d_in[1];
  const float* bq = (const float*)d_in[2];
  const float* Wk = (const float*)d_in[3];
  const float* bk = (const float*)d_in[4];
  const float* Wv = (const float*)d_in[5];
  const float* bv = (const float*)d_in[6];
  const float* Wo = (const float*)d_in[7];
  const float* bo = (const float*)d_in[8];
  float* out = (float*)d_out;

  char* p = (char*)d_ws;
  auto alloc = [&](size_t bytes) { char* r = p; p += (bytes + 255) & ~(size_t)255; return r; };
  unsigned short* hsb  = (unsigned short*)alloc((size_t)M_*E_*2);
  unsigned short* Wqkv = (unsigned short*)alloc((size_t)NQKV_*E_*2);
  unsigned short* Wob  = (unsigned short*)alloc((size_t)E_*E_*2);
  unsigned short* qkv  = (unsigned short*)alloc((size_t)M_*NQKV_*2);
  unsigned short* Vt   = (unsigned short*)alloc((size_t)B_*H_*D_*S_*2);
  unsigned short* Ao   = (unsigned short*)alloc((size_t)M_*E_*2);
  float* biasqkv = (float*)alloc((size_t)NQKV_*4);
  float* cosT = (float*)alloc((size_t)S_*64*4);
  float* sinT = (float*)alloc((size_t)S_*64*4);

  prep_kernel<<<dim3(2048, 5), 256, 0, stream>>>(hs, Wq, Wk, Wv, Wo, bq, bk, bv,
      hsb, Wqkv, Wob, biasqkv, cosT, sinT);
  // Q+K projection with fused RoPE: 256^2 tiles, grid 16x16 = 256 = 1 round.
  gemm8<<<dim3((M_/256)*(2*E_/256)), 512, 0, stream>>>(
      hsb, Wqkv, biasqkv, qkv, cosT, sinT, M_, 2*E_, E_, NQKV_, E_);
  // V projection with fused transpose -> Vt: grid 32x8 = 256 = 1 round.
  gemmVt<<<dim3((M_/128)*(E_/256)), 512, 0, stream>>>(
      hsb, Wqkv + (size_t)2*E_*E_, biasqkv + 2*E_, Vt, M_, E_, E_);
  // attention: 128 q-rows/block, grid 32x16 = 512 = 2 blocks/CU.
  attn_kernel<<<dim3(B_*H_*(S_/128)), 256, 0, stream>>>(qkv, Vt, Ao);
  // Out projection: 128x256 tiles, grid 32x8 = 256 = exactly 1 round.
  gemmA<1><<<dim3((M_/128)*(E_/256)), 512, 0, stream>>>(
      Ao, Wob, bo, out, M_, E_, E_, E_);
}